// Round 5
// baseline (345.795 us; speedup 1.0000x reference)
//
#include <hip/hip_runtime.h>

#define N_NODES 20000
#define N_EDGES 320000
#define NFEAT 14
#define DIM 256

typedef short bf16x8 __attribute__((ext_vector_type(8)));
typedef float f32x4 __attribute__((ext_vector_type(4)));

__device__ __forceinline__ float b2f(unsigned short u) {
    union { unsigned int u; float f; } v; v.u = ((unsigned int)u) << 16; return v.f;
}
__device__ __forceinline__ unsigned short f2b(float f) {
    union { float f; unsigned int u; } v; v.f = f;
    unsigned int r = v.u + 0x7fffu + ((v.u >> 16) & 1u);
    return (unsigned short)(r >> 16);
}

// ---------------- CSR build ----------------

__global__ __launch_bounds__(256) void k_degree(const int* __restrict__ ei, int* __restrict__ cnt) {
    int e = blockIdx.x * 256 + threadIdx.x;
    if (e < N_EDGES) atomicAdd(&cnt[ei[N_EDGES + e]], 1);
}

__global__ __launch_bounds__(1024) void k_scan(const int* __restrict__ cnt,
                                               int* __restrict__ row_ptr,
                                               int* __restrict__ cursor) {
    __shared__ int wsums[16];
    __shared__ int carry;
    int tid = threadIdx.x;
    if (tid == 0) carry = 0;
    __syncthreads();
    for (int base = 0; base < N_NODES; base += 1024) {
        int i = base + tid;
        int v = (i < N_NODES) ? cnt[i] : 0;
        int lane = tid & 63, w = tid >> 6;
        int s = v;
        for (int o = 1; o < 64; o <<= 1) { int t = __shfl_up(s, o); if (lane >= o) s += t; }
        if (lane == 63) wsums[w] = s;
        __syncthreads();
        if (tid < 16) {
            int t = wsums[tid];
            for (int o = 1; o < 16; o <<= 1) { int u = __shfl_up(t, o); if (tid >= o) t += u; }
            wsums[tid] = t;
        }
        __syncthreads();
        int excl = carry + (w ? wsums[w - 1] : 0) + (s - v);
        if (i < N_NODES) { row_ptr[i] = excl; cursor[i] = excl; }
        __syncthreads();
        if (tid == 0) carry += wsums[15];
        __syncthreads();
    }
}

__global__ __launch_bounds__(256) void k_fill(const int* __restrict__ ei, const float* __restrict__ ew,
                                              int* __restrict__ cursor,
                                              int* __restrict__ csr_src, float* __restrict__ csr_w) {
    int e = blockIdx.x * 256 + threadIdx.x;
    if (e < N_EDGES) {
        int d = ei[N_EDGES + e];
        int p = atomicAdd(&cursor[d], 1);
        csr_src[p] = ei[e];
        csr_w[p] = ew[e];
    }
}

// ---------------- weight staging ----------------
// Per 256x256 part p: Wstage[s][c][j] = bf16( W[k = koff + s*32 + j][c] ), s<8, c<256, j<32.
// Parts: 0=W2_rel 1=W2_root 2=W3_rel 3=W3_root 4..6=W_lin rows [256p..256p+256)

__global__ __launch_bounds__(256) void k_wstage(
    const float* __restrict__ W2r, const float* __restrict__ W2o,
    const float* __restrict__ W3r, const float* __restrict__ W3o,
    const float* __restrict__ Wl, unsigned short* __restrict__ out) {
    int part = blockIdx.x >> 8;
    int idx = (blockIdx.x & 255) * 256 + threadIdx.x;   // 0..65535
    int s = idx >> 13, rem = idx & 8191, c = rem >> 5, j = rem & 31;
    const float* W; int koff = 0;
    switch (part) {
        case 0: W = W2r; break;
        case 1: W = W2o; break;
        case 2: W = W3r; break;
        case 3: W = W3o; break;
        default: W = Wl; koff = (part - 4) * 256; break;
    }
    out[(size_t)part * 65536 + idx] = f2b(W[(size_t)(koff + s * 32 + j) * 256 + c]);
}

// ---------------- Layer 1 (K=14, fused, fp32 math, bf16 out) ----------------

__global__ __launch_bounds__(256) void k_layer1(
    const float* __restrict__ x, const int* __restrict__ row_ptr, const int* __restrict__ cnt,
    const int* __restrict__ csr_src, const float* __restrict__ csr_w,
    const float* __restrict__ Wrel, const float* __restrict__ brel, const float* __restrict__ Wroot,
    unsigned short* __restrict__ x1b) {
    __shared__ float sWrel[NFEAT][DIM];
    __shared__ float sWroot[NFEAT][DIM];
    __shared__ float sb[DIM];
    int tid = threadIdx.x;
    for (int i = tid; i < NFEAT * DIM; i += 256) {
        (&sWrel[0][0])[i] = Wrel[i];
        (&sWroot[0][0])[i] = Wroot[i];
    }
    if (tid < DIM) sb[tid] = brel[tid];
    __syncthreads();

    int wv = tid >> 6, lane = tid & 63;
    int node = blockIdx.x * 4 + wv;
    int start = row_ptr[node], deg = cnt[node];

    float acc[NFEAT];
#pragma unroll
    for (int k = 0; k < NFEAT; k++) acc[k] = 0.f;
    for (int e = start + lane; e < start + deg; e += 64) {
        int s = csr_src[e];
        float w = csr_w[e];
        const float2* xr2 = (const float2*)(x + (size_t)s * NFEAT);
#pragma unroll
        for (int k2 = 0; k2 < 7; k2++) {
            float2 v = xr2[k2];
            acc[2 * k2]     += v.x * w;
            acc[2 * k2 + 1] += v.y * w;
        }
    }
#pragma unroll
    for (int k = 0; k < NFEAT; k++) {
        float v = acc[k];
        v += __shfl_xor(v, 1);  v += __shfl_xor(v, 2);  v += __shfl_xor(v, 4);
        v += __shfl_xor(v, 8);  v += __shfl_xor(v, 16); v += __shfl_xor(v, 32);
        acc[k] = v;
    }
    float inv = 1.f / fmaxf((float)deg, 1.f);
    float xr[NFEAT];
#pragma unroll
    for (int k = 0; k < NFEAT; k++) { acc[k] *= inv; xr[k] = x[(size_t)node * NFEAT + k]; }

#pragma unroll
    for (int j = 0; j < 4; j++) {
        int d = lane + 64 * j;
        float o = sb[d];
#pragma unroll
        for (int k = 0; k < NFEAT; k++) o += acc[k] * sWrel[k][d] + xr[k] * sWroot[k][d];
        x1b[(size_t)node * DIM + d] = f2b(fmaxf(o, 0.f));
    }
}

// ---------------- SpMM mean aggregation (bf16 in/out, fp32 accum) ----------------

__global__ __launch_bounds__(256) void k_spmm_mean(
    const unsigned short* __restrict__ xin, const int* __restrict__ row_ptr,
    const int* __restrict__ cnt, const int* __restrict__ csr_src,
    const float* __restrict__ csr_w, unsigned short* __restrict__ meanb) {
    int wv = threadIdx.x >> 6, lane = threadIdx.x & 63;
    int node = blockIdx.x * 4 + wv;
    int start = row_ptr[node], deg = cnt[node];
    float a0 = 0.f, a1 = 0.f, a2 = 0.f, a3 = 0.f;
    for (int e = start; e < start + deg; ++e) {
        int s = csr_src[e];
        float w = csr_w[e];
        ushort4 v = *(const ushort4*)(xin + (size_t)s * DIM + lane * 4);
        a0 += b2f(v.x) * w; a1 += b2f(v.y) * w; a2 += b2f(v.z) * w; a3 += b2f(v.w) * w;
    }
    float inv = 1.f / fmaxf((float)deg, 1.f);
    ushort4 o;
    o.x = f2b(a0 * inv); o.y = f2b(a1 * inv); o.z = f2b(a2 * inv); o.w = f2b(a3 * inv);
    *(ushort4*)(meanb + (size_t)node * DIM + lane * 4) = o;
}

// ---------------- bf16 MFMA multi-part GEMM ----------------
// C[M,256] = act( sum_p A_p[M,256] @ B_p[256,256] + bias ), A_p bf16, B_p in Wstage layout.
// Block: 256 thr = 4 waves; 32 rows x 256 cols per block. Wave (rp,cp): 16 rows x 128 cols.
// 20000 = 625 * 32 -> no row bounds checks.

__global__ __launch_bounds__(256) void k_gemm_mfma(
    const unsigned short* __restrict__ A0, const unsigned short* __restrict__ A1,
    const unsigned short* __restrict__ A2,
    const unsigned short* __restrict__ B0, const unsigned short* __restrict__ B1,
    const unsigned short* __restrict__ B2,
    int nparts, const float* __restrict__ bias,
    unsigned short* __restrict__ outb, float* __restrict__ outf, int do_relu) {
    __shared__ __align__(16) unsigned short Bs[256][40];   // pad 32->40: <=2-way bank conflict
    int t = threadIdx.x;
    int l = t & 63, wv = t >> 6;
    int rowPanel = wv >> 1, colPanel = wv & 1;
    int row0 = blockIdx.x * 32;
    int lr = l & 15, kg = l >> 4;
    int row_a = row0 + rowPanel * 16 + lr;

    f32x4 acc[8];
#pragma unroll
    for (int i = 0; i < 8; i++) acc[i] = (f32x4){0.f, 0.f, 0.f, 0.f};

    for (int p = 0; p < nparts; ++p) {
        const unsigned short* A = (p == 0) ? A0 : (p == 1) ? A1 : A2;
        const unsigned short* B = (p == 0) ? B0 : (p == 1) ? B1 : B2;
        for (int s = 0; s < 8; ++s) {
            // stage B slice [k=32][col=256] stored col-major-in-k: thread t -> col t, 64B
            const int4* src = (const int4*)(B + (size_t)s * 8192 + (size_t)t * 32);
            int4 v0 = src[0], v1 = src[1], v2 = src[2], v3 = src[3];
            *(int4*)&Bs[t][0]  = v0;
            *(int4*)&Bs[t][8]  = v1;
            *(int4*)&Bs[t][16] = v2;
            *(int4*)&Bs[t][24] = v3;
            __syncthreads();
            // A fragment: row = row_a, k = s*32 + kg*8 + j (contiguous 16B)
            bf16x8 a = *(const bf16x8*)(A + (size_t)row_a * DIM + s * 32 + kg * 8);
#pragma unroll
            for (int ct = 0; ct < 8; ++ct) {
                int col = colPanel * 128 + ct * 16 + lr;
                bf16x8 b = *(const bf16x8*)&Bs[col][kg * 8];
                acc[ct] = __builtin_amdgcn_mfma_f32_16x16x32_bf16(a, b, acc[ct], 0, 0, 0);
            }
            __syncthreads();
        }
    }

#pragma unroll
    for (int ct = 0; ct < 8; ++ct) {
        int col = colPanel * 128 + ct * 16 + lr;
        float bv = bias[col];
#pragma unroll
        for (int r = 0; r < 4; ++r) {
            int row = row0 + rowPanel * 16 + kg * 4 + r;
            float v = acc[ct][r] + bv;
            if (do_relu) v = fmaxf(v, 0.f);
            if (outb) outb[(size_t)row * DIM + col] = f2b(v);
            else      outf[(size_t)row * DIM + col] = v;
        }
    }
}

// ---------------- host ----------------

extern "C" void kernel_launch(void* const* d_in, const int* in_sizes, int n_in,
                              void* d_out, int out_size, void* d_ws, size_t ws_size,
                              hipStream_t stream) {
    (void)in_sizes; (void)n_in; (void)out_size; (void)ws_size;
    const float* x       = (const float*)d_in[0];
    const int*   ei      = (const int*)d_in[1];
    const float* ew      = (const float*)d_in[2];
    const float* W1_rel  = (const float*)d_in[3];
    const float* b1      = (const float*)d_in[4];
    const float* W1_root = (const float*)d_in[5];
    const float* W2_rel  = (const float*)d_in[6];
    const float* b2      = (const float*)d_in[7];
    const float* W2_root = (const float*)d_in[8];
    const float* W3_rel  = (const float*)d_in[9];
    const float* b3      = (const float*)d_in[10];
    const float* W3_root = (const float*)d_in[11];
    const float* W_lin   = (const float*)d_in[12];
    const float* b_lin   = (const float*)d_in[13];
    float* out = (float*)d_out;

    char* ws = (char*)d_ws;
    size_t off = 0;
    auto alloc = [&](size_t bytes) -> void* {
        off = (off + 255) & ~(size_t)255;
        void* p = ws + off;
        off += bytes;
        return p;
    };
    int*   cnt     = (int*)alloc((size_t)N_NODES * 4);
    int*   row_ptr = (int*)alloc((size_t)N_NODES * 4);
    int*   cursor  = (int*)alloc((size_t)N_NODES * 4);
    int*   csr_src = (int*)alloc((size_t)N_EDGES * 4);
    float* csr_w   = (float*)alloc((size_t)N_EDGES * 4);
    unsigned short* wst   = (unsigned short*)alloc((size_t)7 * 65536 * 2);
    unsigned short* meanb = (unsigned short*)alloc((size_t)N_NODES * DIM * 2);
    unsigned short* x1b   = (unsigned short*)alloc((size_t)N_NODES * DIM * 2);
    unsigned short* x2b   = (unsigned short*)alloc((size_t)N_NODES * DIM * 2);
    unsigned short* x3b   = (unsigned short*)alloc((size_t)N_NODES * DIM * 2);

    hipMemsetAsync(cnt, 0, (size_t)N_NODES * 4, stream);

    int eblocks = (N_EDGES + 255) / 256;
    k_degree<<<eblocks, 256, 0, stream>>>(ei, cnt);
    k_scan<<<1, 1024, 0, stream>>>(cnt, row_ptr, cursor);
    k_fill<<<eblocks, 256, 0, stream>>>(ei, ew, cursor, csr_src, csr_w);

    k_wstage<<<7 * 256, 256, 0, stream>>>(W2_rel, W2_root, W3_rel, W3_root, W_lin, wst);

    k_layer1<<<N_NODES / 4, 256, 0, stream>>>(x, row_ptr, cnt, csr_src, csr_w,
                                              W1_rel, b1, W1_root, x1b);

    const int ggrid = N_NODES / 32;   // 625

    // layer 2: relu(mean(x1)@W2_rel + x1@W2_root + b2) -> x2b
    k_spmm_mean<<<N_NODES / 4, 256, 0, stream>>>(x1b, row_ptr, cnt, csr_src, csr_w, meanb);
    k_gemm_mfma<<<ggrid, 256, 0, stream>>>(meanb, x1b, nullptr,
                                           wst, wst + 65536, nullptr,
                                           2, b2, x2b, nullptr, 1);

    // layer 3
    k_spmm_mean<<<N_NODES / 4, 256, 0, stream>>>(x2b, row_ptr, cnt, csr_src, csr_w, meanb);
    k_gemm_mfma<<<ggrid, 256, 0, stream>>>(meanb, x2b, nullptr,
                                           wst + 2 * 65536, wst + 3 * 65536, nullptr,
                                           2, b3, x3b, nullptr, 1);

    // final: concat(x1,x2,x3) @ W_lin + b_lin -> fp32 out
    k_gemm_mfma<<<ggrid, 256, 0, stream>>>(x1b, x2b, x3b,
                                           wst + 4 * 65536, wst + 5 * 65536, wst + 6 * 65536,
                                           3, b_lin, nullptr, out, 0);
}